// Round 1
// baseline (2813.895 us; speedup 1.0000x reference)
//
#include <hip/hip_runtime.h>
#include <stdint.h>

#define NN 50000   // nodes
#define NE 100000  // edges
#define DD 768     // feature dim
#define KC 1536    // concatenated K = 2*DD

typedef __attribute__((ext_vector_type(8))) __bf16 bf16x8;
typedef __attribute__((ext_vector_type(4))) float floatx4;

static __device__ __forceinline__ float bf2f(unsigned short u) {
    union { unsigned int u; float f; } c; c.u = ((unsigned int)u) << 16; return c.f;
}
static __device__ __forceinline__ unsigned short f2bf(float f) {
    union { float f; unsigned int u; } c; c.f = f;
    return (unsigned short)((c.u + 0x7FFFu + ((c.u >> 16) & 1u)) >> 16);
}

// async global->LDS, 16B per lane; LDS dst = wave-uniform base + lane*16
static __device__ __forceinline__ void gld16(const void* g, void* l) {
    __builtin_amdgcn_global_load_lds(
        (const __attribute__((address_space(1))) unsigned int*)g,
        (__attribute__((address_space(3))) unsigned int*)l, 16, 0, 0);
}

// ---------------- prep kernels ----------------

// x (f32) -> bf16 into right half of Acat1 ([n][768..1535])
__global__ __launch_bounds__(192) void k_convert_x(const float* __restrict__ x,
                                                   unsigned short* __restrict__ acat) {
    const int n = blockIdx.x;
    const int c = threadIdx.x * 4;
    const float4 v = *(const float4*)(x + (size_t)n * DD + c);
    ushort4 o;
    o.x = f2bf(v.x); o.y = f2bf(v.y); o.z = f2bf(v.z); o.w = f2bf(v.w);
    *(ushort4*)(acat + (size_t)n * KC + DD + c) = o;
}

// Bcat[layer][j][k] = k<768 ? Wl[j][k] : Wr[j][k-768]   (bf16)
__global__ __launch_bounds__(384) void k_convert_w(const float* __restrict__ W1l,
                                                   const float* __restrict__ W1r,
                                                   const float* __restrict__ W2l,
                                                   const float* __restrict__ W2r,
                                                   unsigned short* __restrict__ B1,
                                                   unsigned short* __restrict__ B2) {
    const int j = blockIdx.x;
    const int layer = blockIdx.y;
    const int k = threadIdx.x * 4;
    const float* Wl = layer ? W2l : W1l;
    const float* Wr = layer ? W2r : W1r;
    unsigned short* B = layer ? B2 : B1;
    const float4 v = (k < DD) ? *(const float4*)(Wl + (size_t)j * DD + k)
                              : *(const float4*)(Wr + (size_t)j * DD + (k - DD));
    ushort4 o; o.x = f2bf(v.x); o.y = f2bf(v.y); o.z = f2bf(v.z); o.w = f2bf(v.w);
    *(ushort4*)(B + (size_t)j * KC + k) = o;
}

__global__ __launch_bounds__(256) void k_deg(const int* __restrict__ dst,
                                             float* __restrict__ deg) {
    int e = blockIdx.x * 256 + threadIdx.x;
    if (e < NE) atomicAdd(&deg[dst[e]], 1.0f);
}

// agg[dst[e]] += x[src[e]]  (f32 source), one block per edge
__global__ __launch_bounds__(192) void k_scatter_f32(const float* __restrict__ x,
                                                     const int* __restrict__ src,
                                                     const int* __restrict__ dst,
                                                     float* __restrict__ agg) {
    const int e = blockIdx.x;
    const int c = threadIdx.x * 4;
    const int s = src[e], d = dst[e];
    const float4 v = *(const float4*)(x + (size_t)s * DD + c);
    float* p = agg + (size_t)d * DD + c;
    atomicAdd(p + 0, v.x); atomicAdd(p + 1, v.y);
    atomicAdd(p + 2, v.z); atomicAdd(p + 3, v.w);
}

// agg[dst[e]] += h[src[e]]  (bf16 source = right half of Acat2)
__global__ __launch_bounds__(192) void k_scatter_bf16(const unsigned short* __restrict__ h,
                                                      const int* __restrict__ src,
                                                      const int* __restrict__ dst,
                                                      float* __restrict__ agg) {
    const int e = blockIdx.x;
    const int c = threadIdx.x * 4;
    const int s = src[e], d = dst[e];
    const ushort4 v = *(const ushort4*)(h + (size_t)s * KC + DD + c);
    float* p = agg + (size_t)d * DD + c;
    atomicAdd(p + 0, bf2f(v.x)); atomicAdd(p + 1, bf2f(v.y));
    atomicAdd(p + 2, bf2f(v.z)); atomicAdd(p + 3, bf2f(v.w));
}

// Acat[n][0..767] = bf16(agg[n][c] / max(deg[n],1))
__global__ __launch_bounds__(192) void k_divide(const float* __restrict__ agg,
                                                const float* __restrict__ deg,
                                                unsigned short* __restrict__ acat) {
    const int n = blockIdx.x;
    const int c = threadIdx.x * 4;
    const float inv = 1.0f / fmaxf(deg[n], 1.0f);
    const float4 v = *(const float4*)(agg + (size_t)n * DD + c);
    ushort4 o;
    o.x = f2bf(v.x * inv); o.y = f2bf(v.y * inv);
    o.z = f2bf(v.z * inv); o.w = f2bf(v.w * inv);
    *(ushort4*)(acat + (size_t)n * KC + c) = o;
}

// ---------------- GEMM: C[M x 768] = A[M x 1536] * B[768 x 1536]^T + bias ----
// m97 structure: 128x128 tile, BK=32, 4 waves, 4x4 16x16 subtiles per wave.
// MODE 0: +bias, relu, store bf16 into right half of Acat2
// MODE 1: +bias, store f32 to out
template <int MODE>
__global__ __launch_bounds__(256) void k_gemm(const unsigned short* __restrict__ A,
                                              const unsigned short* __restrict__ B,
                                              const float* __restrict__ bias,
                                              unsigned short* __restrict__ outA,
                                              float* __restrict__ outF) {
    __shared__ alignas(16) unsigned short sA[128 * 32];
    __shared__ alignas(16) unsigned short sB[128 * 32];
    const int tid = threadIdx.x;
    const int w = tid >> 6, lane = tid & 63;
    const int quad = lane >> 4, r16 = lane & 15;
    const int wm = (w & 1) * 64, wn = (w >> 1) * 64;
    const int tm = blockIdx.y, tn = blockIdx.x;
    const int rowBase = tm * 128;

    floatx4 acc[4][4];
#pragma unroll
    for (int i = 0; i < 4; ++i)
#pragma unroll
        for (int j = 0; j < 4; ++j) acc[i][j] = (floatx4){0.f, 0.f, 0.f, 0.f};

    for (int kt = 0; kt < KC / 32; ++kt) {
        const int k0 = kt * 32;
        // stage A/B tiles: 512 chunks of 16B each per tile; 4 waves x 2 calls
#pragma unroll
        for (int q = 0; q < 2; ++q) {
            const int c0 = (w * 2 + q) * 64;
            const int c = c0 + lane;
            const int row = c >> 2;
            const int col = (c & 3) * 8;
            int gr = rowBase + row; if (gr > NN - 1) gr = NN - 1;  // clamp tail tile
            gld16(A + (size_t)gr * KC + k0 + col, sA + (size_t)c0 * 8);
            gld16(B + (size_t)(tn * 128 + row) * KC + k0 + col, sB + (size_t)c0 * 8);
        }
        __syncthreads();
        bf16x8 af[4], bfr[4];
#pragma unroll
        for (int i = 0; i < 4; ++i)
            af[i] = *(const bf16x8*)(sA + (wm + i * 16 + r16) * 32 + quad * 8);
#pragma unroll
        for (int j = 0; j < 4; ++j)
            bfr[j] = *(const bf16x8*)(sB + (wn + j * 16 + r16) * 32 + quad * 8);
#pragma unroll
        for (int i = 0; i < 4; ++i)
#pragma unroll
            for (int j = 0; j < 4; ++j)
                acc[i][j] = __builtin_amdgcn_mfma_f32_16x16x32_bf16(af[i], bfr[j], acc[i][j], 0, 0, 0);
        __syncthreads();
    }

    // epilogue: C/D layout col=lane&15, row=quad*4+reg
#pragma unroll
    for (int i = 0; i < 4; ++i)
#pragma unroll
        for (int j = 0; j < 4; ++j) {
            const int gcol = tn * 128 + wn + j * 16 + r16;
            const float bv = bias[gcol];
#pragma unroll
            for (int rr = 0; rr < 4; ++rr) {
                const int grow = rowBase + wm + i * 16 + quad * 4 + rr;
                if (grow < NN) {
                    float v = acc[i][j][rr] + bv;
                    if (MODE == 0) {
                        v = fmaxf(v, 0.0f);
                        outA[(size_t)grow * KC + DD + gcol] = f2bf(v);
                    } else {
                        outF[(size_t)grow * DD + gcol] = v;
                    }
                }
            }
        }
}

extern "C" void kernel_launch(void* const* d_in, const int* in_sizes, int n_in,
                              void* d_out, int out_size, void* d_ws, size_t ws_size,
                              hipStream_t stream) {
    const float* x   = (const float*)d_in[0];
    const int*   ei  = (const int*)d_in[1];
    const float* W1l = (const float*)d_in[2];
    const float* b1l = (const float*)d_in[3];
    const float* W1r = (const float*)d_in[4];
    const float* W2l = (const float*)d_in[5];
    const float* b2l = (const float*)d_in[6];
    const float* W2r = (const float*)d_in[7];
    const int* src = ei;
    const int* dst = ei + NE;
    float* out = (float*)d_out;

    // ws layout (totals ~312 MB):
    //   Acat1: [N x 1536] bf16  (left=agg1, right=x)
    //   Acat2: [N x 1536] bf16  (left=agg2, right=h)
    //   B1,B2: [768 x 1536] bf16 each
    //   deg:   [N] f32
    // f32 accumulators: layer1 -> d_out (dead until GEMM2); layer2 -> Acat1 bytes (dead after GEMM1)
    char* ws = (char*)d_ws;
    unsigned short* Acat1 = (unsigned short*)ws;
    unsigned short* Acat2 = (unsigned short*)(ws + (size_t)NN * KC * 2);
    unsigned short* B1    = (unsigned short*)(ws + (size_t)NN * KC * 4);
    unsigned short* B2    = B1 + (size_t)DD * KC;
    float* deg  = (float*)(ws + (size_t)NN * KC * 4 + (size_t)DD * KC * 4);
    float* agg1 = out;
    float* agg2 = (float*)Acat1;

    hipMemsetAsync(agg1, 0, (size_t)NN * DD * 4, stream);
    hipMemsetAsync(deg, 0, (size_t)NN * 4, stream);

    k_convert_x<<<NN, 192, 0, stream>>>(x, Acat1);
    dim3 wgrid(DD, 2);
    k_convert_w<<<wgrid, 384, 0, stream>>>(W1l, W1r, W2l, W2r, B1, B2);
    k_deg<<<(NE + 255) / 256, 256, 0, stream>>>(dst, deg);
    k_scatter_f32<<<NE, 192, 0, stream>>>(x, src, dst, agg1);
    k_divide<<<NN, 192, 0, stream>>>(agg1, deg, Acat1);

    dim3 ggrid(DD / 128, (NN + 127) / 128);
    k_gemm<0><<<ggrid, 256, 0, stream>>>(Acat1, B1, b1l, Acat2, nullptr);

    hipMemsetAsync(agg2, 0, (size_t)NN * DD * 4, stream);
    k_scatter_bf16<<<NE, 192, 0, stream>>>(Acat2, src, dst, agg2);
    k_divide<<<NN, 192, 0, stream>>>(agg2, deg, Acat2);

    k_gemm<1><<<ggrid, 256, 0, stream>>>(Acat2, B2, b2l, nullptr, out);
}

// Round 2
// 900.711 us; speedup vs baseline: 3.1241x; 3.1241x over previous
//
#include <hip/hip_runtime.h>
#include <stdint.h>

#define NN 50000   // nodes
#define NE 100000  // edges
#define DD 768     // feature dim
#define KC 1536    // concatenated K = 2*DD

typedef __attribute__((ext_vector_type(8))) __bf16 bf16x8;
typedef __attribute__((ext_vector_type(4))) float floatx4;

static __device__ __forceinline__ float bf2f(unsigned short u) {
    union { unsigned int u; float f; } c; c.u = ((unsigned int)u) << 16; return c.f;
}
static __device__ __forceinline__ unsigned short f2bf(float f) {
    union { float f; unsigned int u; } c; c.f = f;
    return (unsigned short)((c.u + 0x7FFFu + ((c.u >> 16) & 1u)) >> 16);
}

// async global->LDS, 16B per lane; LDS dst = wave-uniform base + lane*16
static __device__ __forceinline__ void gld16(const void* g, void* l) {
    __builtin_amdgcn_global_load_lds(
        (const __attribute__((address_space(1))) unsigned int*)g,
        (__attribute__((address_space(3))) unsigned int*)l, 16, 0, 0);
}

// ---------------- prep kernels ----------------

// x (f32) -> bf16 into right half of Acat1 ([n][768..1535])
__global__ __launch_bounds__(192) void k_convert_x(const float* __restrict__ x,
                                                   unsigned short* __restrict__ acat) {
    const int n = blockIdx.x;
    const int c = threadIdx.x * 4;
    const float4 v = *(const float4*)(x + (size_t)n * DD + c);
    ushort4 o;
    o.x = f2bf(v.x); o.y = f2bf(v.y); o.z = f2bf(v.z); o.w = f2bf(v.w);
    *(ushort4*)(acat + (size_t)n * KC + DD + c) = o;
}

// Bcat[layer][j][k] = k<768 ? Wl[j][k] : Wr[j][k-768]   (bf16)
__global__ __launch_bounds__(384) void k_convert_w(const float* __restrict__ W1l,
                                                   const float* __restrict__ W1r,
                                                   const float* __restrict__ W2l,
                                                   const float* __restrict__ W2r,
                                                   unsigned short* __restrict__ B1,
                                                   unsigned short* __restrict__ B2) {
    const int j = blockIdx.x;
    const int layer = blockIdx.y;
    const int k = threadIdx.x * 4;
    const float* Wl = layer ? W2l : W1l;
    const float* Wr = layer ? W2r : W1r;
    unsigned short* B = layer ? B2 : B1;
    const float4 v = (k < DD) ? *(const float4*)(Wl + (size_t)j * DD + k)
                              : *(const float4*)(Wr + (size_t)j * DD + (k - DD));
    ushort4 o; o.x = f2bf(v.x); o.y = f2bf(v.y); o.z = f2bf(v.z); o.w = f2bf(v.w);
    *(ushort4*)(B + (size_t)j * KC + k) = o;
}

// ---------------- CSR build (by dst) ----------------

__global__ __launch_bounds__(256) void k_hist(const int* __restrict__ dst,
                                              int* __restrict__ cnt) {
    int e = blockIdx.x * 256 + threadIdx.x;
    if (e < NE) atomicAdd(&cnt[dst[e]], 1);
}

// single-block exclusive scan: rowptr[0]=0, rowptr[i+1]=sum(cnt[0..i])
__global__ __launch_bounds__(1024) void k_scan(const int* __restrict__ cnt,
                                               int* __restrict__ rowptr) {
    __shared__ int buf[1024];
    __shared__ int carry;
    if (threadIdx.x == 0) { carry = 0; rowptr[0] = 0; }
    __syncthreads();
    for (int base = 0; base < NN; base += 1024) {
        const int i = base + threadIdx.x;
        int v = (i < NN) ? cnt[i] : 0;
        buf[threadIdx.x] = v;
        __syncthreads();
#pragma unroll
        for (int off = 1; off < 1024; off <<= 1) {
            int t = (threadIdx.x >= off) ? buf[threadIdx.x - off] : 0;
            __syncthreads();
            buf[threadIdx.x] += t;
            __syncthreads();
        }
        const int incl = buf[threadIdx.x];
        const int total = buf[1023];
        if (i < NN) rowptr[i + 1] = carry + incl;
        __syncthreads();
        if (threadIdx.x == 0) carry += total;
        __syncthreads();
    }
}

__global__ __launch_bounds__(256) void k_fill(const int* __restrict__ src,
                                              const int* __restrict__ dst,
                                              const int* __restrict__ rowptr,
                                              int* __restrict__ cursor,
                                              int* __restrict__ esrc) {
    int e = blockIdx.x * 256 + threadIdx.x;
    if (e < NE) {
        const int d = dst[e];
        const int pos = atomicAdd(&cursor[d], 1);
        esrc[rowptr[d] + pos] = src[e];
    }
}

// ---------------- aggregation by gather (no atomics) ----------------

// layer 1: gather f32 x rows, mean, write bf16 into left half of Acat1
__global__ __launch_bounds__(192) void k_agg_f32(const float* __restrict__ x,
                                                 const int* __restrict__ rowptr,
                                                 const int* __restrict__ esrc,
                                                 unsigned short* __restrict__ acat) {
    const int n = blockIdx.x;
    const int c = threadIdx.x * 4;
    const int beg = rowptr[n], end = rowptr[n + 1];
    float4 a = {0.f, 0.f, 0.f, 0.f};
    for (int e = beg; e < end; ++e) {
        const int s = esrc[e];
        const float4 v = *(const float4*)(x + (size_t)s * DD + c);
        a.x += v.x; a.y += v.y; a.z += v.z; a.w += v.w;
    }
    const float inv = (end > beg) ? 1.0f / (float)(end - beg) : 1.0f;
    ushort4 o;
    o.x = f2bf(a.x * inv); o.y = f2bf(a.y * inv);
    o.z = f2bf(a.z * inv); o.w = f2bf(a.w * inv);
    *(ushort4*)(acat + (size_t)n * KC + c) = o;
}

// layer 2: gather bf16 h rows (right half of Acat2), mean, write bf16 left half
__global__ __launch_bounds__(192) void k_agg_bf16(const unsigned short* __restrict__ hcat,
                                                  const int* __restrict__ rowptr,
                                                  const int* __restrict__ esrc,
                                                  unsigned short* __restrict__ acat) {
    const int n = blockIdx.x;
    const int c = threadIdx.x * 4;
    const int beg = rowptr[n], end = rowptr[n + 1];
    float4 a = {0.f, 0.f, 0.f, 0.f};
    for (int e = beg; e < end; ++e) {
        const int s = esrc[e];
        const ushort4 v = *(const ushort4*)(hcat + (size_t)s * KC + DD + c);
        a.x += bf2f(v.x); a.y += bf2f(v.y); a.z += bf2f(v.z); a.w += bf2f(v.w);
    }
    const float inv = (end > beg) ? 1.0f / (float)(end - beg) : 1.0f;
    ushort4 o;
    o.x = f2bf(a.x * inv); o.y = f2bf(a.y * inv);
    o.z = f2bf(a.z * inv); o.w = f2bf(a.w * inv);
    *(ushort4*)(acat + (size_t)n * KC + c) = o;
}

// ---------------- GEMM: C[M x 768] = A[M x 1536] * B[768 x 1536]^T + bias ----
// m97 structure: 128x128 tile, BK=32, 4 waves, 4x4 16x16 subtiles per wave.
// MODE 0: +bias, relu, store bf16 into right half of Acat2
// MODE 1: +bias, store f32 to out
template <int MODE>
__global__ __launch_bounds__(256) void k_gemm(const unsigned short* __restrict__ A,
                                              const unsigned short* __restrict__ B,
                                              const float* __restrict__ bias,
                                              unsigned short* __restrict__ outA,
                                              float* __restrict__ outF) {
    __shared__ alignas(16) unsigned short sA[128 * 32];
    __shared__ alignas(16) unsigned short sB[128 * 32];
    const int tid = threadIdx.x;
    const int w = tid >> 6, lane = tid & 63;
    const int quad = lane >> 4, r16 = lane & 15;
    const int wm = (w & 1) * 64, wn = (w >> 1) * 64;
    const int tm = blockIdx.y, tn = blockIdx.x;
    const int rowBase = tm * 128;

    floatx4 acc[4][4];
#pragma unroll
    for (int i = 0; i < 4; ++i)
#pragma unroll
        for (int j = 0; j < 4; ++j) acc[i][j] = (floatx4){0.f, 0.f, 0.f, 0.f};

    for (int kt = 0; kt < KC / 32; ++kt) {
        const int k0 = kt * 32;
#pragma unroll
        for (int q = 0; q < 2; ++q) {
            const int c0 = (w * 2 + q) * 64;
            const int c = c0 + lane;
            const int row = c >> 2;
            const int col = (c & 3) * 8;
            int gr = rowBase + row; if (gr > NN - 1) gr = NN - 1;  // clamp tail tile
            gld16(A + (size_t)gr * KC + k0 + col, sA + (size_t)c0 * 8);
            gld16(B + (size_t)(tn * 128 + row) * KC + k0 + col, sB + (size_t)c0 * 8);
        }
        __syncthreads();
        bf16x8 af[4], bfr[4];
#pragma unroll
        for (int i = 0; i < 4; ++i)
            af[i] = *(const bf16x8*)(sA + (wm + i * 16 + r16) * 32 + quad * 8);
#pragma unroll
        for (int j = 0; j < 4; ++j)
            bfr[j] = *(const bf16x8*)(sB + (wn + j * 16 + r16) * 32 + quad * 8);
#pragma unroll
        for (int i = 0; i < 4; ++i)
#pragma unroll
            for (int j = 0; j < 4; ++j)
                acc[i][j] = __builtin_amdgcn_mfma_f32_16x16x32_bf16(af[i], bfr[j], acc[i][j], 0, 0, 0);
        __syncthreads();
    }

    // epilogue: C/D layout col=lane&15, row=quad*4+reg
#pragma unroll
    for (int i = 0; i < 4; ++i)
#pragma unroll
        for (int j = 0; j < 4; ++j) {
            const int gcol = tn * 128 + wn + j * 16 + r16;
            const float bv = bias[gcol];
#pragma unroll
            for (int rr = 0; rr < 4; ++rr) {
                const int grow = rowBase + wm + i * 16 + quad * 4 + rr;
                if (grow < NN) {
                    float v = acc[i][j][rr] + bv;
                    if (MODE == 0) {
                        v = fmaxf(v, 0.0f);
                        outA[(size_t)grow * KC + DD + gcol] = f2bf(v);
                    } else {
                        outF[(size_t)grow * DD + gcol] = v;
                    }
                }
            }
        }
}

extern "C" void kernel_launch(void* const* d_in, const int* in_sizes, int n_in,
                              void* d_out, int out_size, void* d_ws, size_t ws_size,
                              hipStream_t stream) {
    const float* x   = (const float*)d_in[0];
    const int*   ei  = (const int*)d_in[1];
    const float* W1l = (const float*)d_in[2];
    const float* b1l = (const float*)d_in[3];
    const float* W1r = (const float*)d_in[4];
    const float* W2l = (const float*)d_in[5];
    const float* b2l = (const float*)d_in[6];
    const float* W2r = (const float*)d_in[7];
    const int* src = ei;
    const int* dst = ei + NE;
    float* out = (float*)d_out;

    // ws layout (~310 MB):
    //   Acat1: [N x 1536] bf16  (left=agg1, right=x)
    //   Acat2: [N x 1536] bf16  (left=agg2, right=h)
    //   B1,B2: [768 x 1536] bf16 each
    //   CSR:   cnt[N] (reused as cursor), rowptr[N+1], esrc[E]
    char* ws = (char*)d_ws;
    unsigned short* Acat1 = (unsigned short*)ws;
    unsigned short* Acat2 = (unsigned short*)(ws + (size_t)NN * KC * 2);
    unsigned short* B1    = (unsigned short*)(ws + (size_t)NN * KC * 4);
    unsigned short* B2    = B1 + (size_t)DD * KC;
    int* cnt    = (int*)(ws + (size_t)NN * KC * 4 + (size_t)DD * KC * 4);
    int* rowptr = cnt + NN;
    int* esrc   = rowptr + NN + 1;

    // CSR build
    hipMemsetAsync(cnt, 0, NN * sizeof(int), stream);
    k_hist<<<(NE + 255) / 256, 256, 0, stream>>>(dst, cnt);
    k_scan<<<1, 1024, 0, stream>>>(cnt, rowptr);
    hipMemsetAsync(cnt, 0, NN * sizeof(int), stream);  // reuse as cursor
    k_fill<<<(NE + 255) / 256, 256, 0, stream>>>(src, dst, rowptr, cnt, esrc);

    // converts (independent of CSR)
    k_convert_x<<<NN, 192, 0, stream>>>(x, Acat1);
    dim3 wgrid(DD, 2);
    k_convert_w<<<wgrid, 384, 0, stream>>>(W1l, W1r, W2l, W2r, B1, B2);

    // layer 1
    k_agg_f32<<<NN, 192, 0, stream>>>(x, rowptr, esrc, Acat1);
    dim3 ggrid(DD / 128, (NN + 127) / 128);
    k_gemm<0><<<ggrid, 256, 0, stream>>>(Acat1, B1, b1l, Acat2, nullptr);

    // layer 2
    k_agg_bf16<<<NN, 192, 0, stream>>>(Acat2, rowptr, esrc, Acat2);
    k_gemm<1><<<ggrid, 256, 0, stream>>>(Acat2, B2, b2l, nullptr, out);
}

// Round 3
// 775.108 us; speedup vs baseline: 3.6303x; 1.1620x over previous
//
#include <hip/hip_runtime.h>
#include <stdint.h>

#define NN 50000   // nodes
#define NE 100000  // edges
#define DD 768     // feature dim
#define KC 1536    // concatenated K = 2*DD
#define SCAN_B 196 // ceil(NN/256)

typedef __attribute__((ext_vector_type(8))) __bf16 bf16x8;
typedef __attribute__((ext_vector_type(4))) float floatx4;

static __device__ __forceinline__ float bf2f(unsigned short u) {
    union { unsigned int u; float f; } c; c.u = ((unsigned int)u) << 16; return c.f;
}
static __device__ __forceinline__ unsigned short f2bf(float f) {
    union { float f; unsigned int u; } c; c.f = f;
    return (unsigned short)((c.u + 0x7FFFu + ((c.u >> 16) & 1u)) >> 16);
}

// async global->LDS, 16B per lane; LDS dst = wave-uniform base + lane*16
static __device__ __forceinline__ void gld16(const void* g, void* l) {
    __builtin_amdgcn_global_load_lds(
        (const __attribute__((address_space(1))) unsigned int*)g,
        (__attribute__((address_space(3))) unsigned int*)l, 16, 0, 0);
}

// ---------------- prep kernels ----------------

// x (f32) -> bf16 into right half of Acat1 ([n][768..1535])
__global__ __launch_bounds__(192) void k_convert_x(const float* __restrict__ x,
                                                   unsigned short* __restrict__ acat) {
    const int n = blockIdx.x;
    const int c = threadIdx.x * 4;
    const float4 v = *(const float4*)(x + (size_t)n * DD + c);
    ushort4 o;
    o.x = f2bf(v.x); o.y = f2bf(v.y); o.z = f2bf(v.z); o.w = f2bf(v.w);
    *(ushort4*)(acat + (size_t)n * KC + DD + c) = o;
}

// Bcat[layer][j][k] = k<768 ? Wl[j][k] : Wr[j][k-768]   (bf16)
__global__ __launch_bounds__(384) void k_convert_w(const float* __restrict__ W1l,
                                                   const float* __restrict__ W1r,
                                                   const float* __restrict__ W2l,
                                                   const float* __restrict__ W2r,
                                                   unsigned short* __restrict__ B1,
                                                   unsigned short* __restrict__ B2) {
    const int j = blockIdx.x;
    const int layer = blockIdx.y;
    const int k = threadIdx.x * 4;
    const float* Wl = layer ? W2l : W1l;
    const float* Wr = layer ? W2r : W1r;
    unsigned short* B = layer ? B2 : B1;
    const float4 v = (k < DD) ? *(const float4*)(Wl + (size_t)j * DD + k)
                              : *(const float4*)(Wr + (size_t)j * DD + (k - DD));
    ushort4 o; o.x = f2bf(v.x); o.y = f2bf(v.y); o.z = f2bf(v.z); o.w = f2bf(v.w);
    *(ushort4*)(B + (size_t)j * KC + k) = o;
}

// ---------------- CSR build (by dst) ----------------

__global__ __launch_bounds__(256) void k_hist(const int* __restrict__ dst,
                                              int* __restrict__ cnt) {
    int e = blockIdx.x * 256 + threadIdx.x;
    if (e < NE) atomicAdd(&cnt[dst[e]], 1);
}

// hierarchical scan, stage 1: per-block inclusive scan of 256-elem chunks
__global__ __launch_bounds__(256) void k_scan1(const int* __restrict__ cnt,
                                               int* __restrict__ rowptr,
                                               int* __restrict__ partial) {
    __shared__ int buf[256];
    const int t = threadIdx.x;
    const int i = blockIdx.x * 256 + t;
    int v = (i < NN) ? cnt[i] : 0;
    buf[t] = v;
    __syncthreads();
#pragma unroll
    for (int off = 1; off < 256; off <<= 1) {
        int u = (t >= off) ? buf[t - off] : 0;
        __syncthreads();
        buf[t] += u;
        __syncthreads();
    }
    if (i < NN) rowptr[i + 1] = buf[t];
    if (t == 255) partial[blockIdx.x] = buf[255];
}

// stage 2: single block, exclusive scan of SCAN_B partials
__global__ __launch_bounds__(256) void k_scan2(int* __restrict__ partial) {
    __shared__ int buf[256];
    const int t = threadIdx.x;
    int v = (t < SCAN_B) ? partial[t] : 0;
    buf[t] = v;
    __syncthreads();
#pragma unroll
    for (int off = 1; off < 256; off <<= 1) {
        int u = (t >= off) ? buf[t - off] : 0;
        __syncthreads();
        buf[t] += u;
        __syncthreads();
    }
    if (t < SCAN_B) partial[t] = buf[t] - v;  // exclusive
}

// stage 3: add block offsets, set rowptr[0]
__global__ __launch_bounds__(256) void k_scan3(int* __restrict__ rowptr,
                                               const int* __restrict__ partial) {
    const int i = blockIdx.x * 256 + threadIdx.x;
    if (i < NN) rowptr[i + 1] += partial[blockIdx.x];
    if (i == 0) rowptr[0] = 0;
}

__global__ __launch_bounds__(256) void k_fill(const int* __restrict__ src,
                                              const int* __restrict__ dst,
                                              const int* __restrict__ rowptr,
                                              int* __restrict__ cursor,
                                              int* __restrict__ esrc) {
    int e = blockIdx.x * 256 + threadIdx.x;
    if (e < NE) {
        const int d = dst[e];
        const int pos = atomicAdd(&cursor[d], 1);
        esrc[rowptr[d] + pos] = src[e];
    }
}

// ---------------- aggregation by gather (no atomics) ----------------
// gather bf16 rows from right half of srcmat, mean in f32, write bf16 left half of dstmat
__global__ __launch_bounds__(192) void k_agg(const unsigned short* __restrict__ srcmat,
                                             const int* __restrict__ rowptr,
                                             const int* __restrict__ esrc,
                                             unsigned short* __restrict__ dstmat) {
    const int n = blockIdx.x;
    const int c = threadIdx.x * 4;
    const int beg = rowptr[n], end = rowptr[n + 1];
    float4 a = {0.f, 0.f, 0.f, 0.f};
    for (int e = beg; e < end; ++e) {
        const int s = esrc[e];
        const ushort4 v = *(const ushort4*)(srcmat + (size_t)s * KC + DD + c);
        a.x += bf2f(v.x); a.y += bf2f(v.y); a.z += bf2f(v.z); a.w += bf2f(v.w);
    }
    const float inv = (end > beg) ? 1.0f / (float)(end - beg) : 1.0f;
    ushort4 o;
    o.x = f2bf(a.x * inv); o.y = f2bf(a.y * inv);
    o.z = f2bf(a.z * inv); o.w = f2bf(a.w * inv);
    *(ushort4*)(dstmat + (size_t)n * KC + c) = o;
}

// ---------------- GEMM: C[M x 768] = A[M x 1536] * B[768 x 1536]^T + bias ----
// m97 structure. Grid: x = tm (fast, L3 A-streaming), y = tn.
// MODE 0: +bias, relu, store bf16 into right half of Acat2
// MODE 1: +bias, store f32 to out
template <int MODE>
__global__ __launch_bounds__(256) void k_gemm(const unsigned short* __restrict__ A,
                                              const unsigned short* __restrict__ B,
                                              const float* __restrict__ bias,
                                              unsigned short* __restrict__ outA,
                                              float* __restrict__ outF) {
    __shared__ alignas(16) unsigned short sA[128 * 32];
    __shared__ alignas(16) unsigned short sB[128 * 32];
    const int tid = threadIdx.x;
    const int w = tid >> 6, lane = tid & 63;
    const int quad = lane >> 4, r16 = lane & 15;
    const int wm = (w & 1) * 64, wn = (w >> 1) * 64;
    const int tm = blockIdx.x, tn = blockIdx.y;
    const int rowBase = tm * 128;

    floatx4 acc[4][4];
#pragma unroll
    for (int i = 0; i < 4; ++i)
#pragma unroll
        for (int j = 0; j < 4; ++j) acc[i][j] = (floatx4){0.f, 0.f, 0.f, 0.f};

    for (int kt = 0; kt < KC / 32; ++kt) {
        const int k0 = kt * 32;
#pragma unroll
        for (int q = 0; q < 2; ++q) {
            const int c0 = (w * 2 + q) * 64;
            const int c = c0 + lane;
            const int row = c >> 2;
            const int col = (c & 3) * 8;
            int gr = rowBase + row; if (gr > NN - 1) gr = NN - 1;  // clamp tail tile
            gld16(A + (size_t)gr * KC + k0 + col, sA + (size_t)c0 * 8);
            gld16(B + (size_t)(tn * 128 + row) * KC + k0 + col, sB + (size_t)c0 * 8);
        }
        __syncthreads();
        bf16x8 af[4], bfr[4];
#pragma unroll
        for (int i = 0; i < 4; ++i)
            af[i] = *(const bf16x8*)(sA + (wm + i * 16 + r16) * 32 + quad * 8);
#pragma unroll
        for (int j = 0; j < 4; ++j)
            bfr[j] = *(const bf16x8*)(sB + (wn + j * 16 + r16) * 32 + quad * 8);
#pragma unroll
        for (int i = 0; i < 4; ++i)
#pragma unroll
            for (int j = 0; j < 4; ++j)
                acc[i][j] = __builtin_amdgcn_mfma_f32_16x16x32_bf16(af[i], bfr[j], acc[i][j], 0, 0, 0);
        __syncthreads();
    }

    // epilogue: C/D layout col=lane&15, row=quad*4+reg
#pragma unroll
    for (int i = 0; i < 4; ++i)
#pragma unroll
        for (int j = 0; j < 4; ++j) {
            const int gcol = tn * 128 + wn + j * 16 + r16;
            const float bv = bias[gcol];
#pragma unroll
            for (int rr = 0; rr < 4; ++rr) {
                const int grow = rowBase + wm + i * 16 + quad * 4 + rr;
                if (grow < NN) {
                    float v = acc[i][j][rr] + bv;
                    if (MODE == 0) {
                        v = fmaxf(v, 0.0f);
                        outA[(size_t)grow * KC + DD + gcol] = f2bf(v);
                    } else {
                        outF[(size_t)grow * DD + gcol] = v;
                    }
                }
            }
        }
}

extern "C" void kernel_launch(void* const* d_in, const int* in_sizes, int n_in,
                              void* d_out, int out_size, void* d_ws, size_t ws_size,
                              hipStream_t stream) {
    const float* x   = (const float*)d_in[0];
    const int*   ei  = (const int*)d_in[1];
    const float* W1l = (const float*)d_in[2];
    const float* b1l = (const float*)d_in[3];
    const float* W1r = (const float*)d_in[4];
    const float* W2l = (const float*)d_in[5];
    const float* b2l = (const float*)d_in[6];
    const float* W2r = (const float*)d_in[7];
    const int* src = ei;
    const int* dst = ei + NE;
    float* out = (float*)d_out;

    // ws layout (~310 MB):
    //   Acat1: [N x 1536] bf16  (left=agg1, right=bf16(x))
    //   Acat2: [N x 1536] bf16  (left=agg2, right=h)
    //   B1,B2: [768 x 1536] bf16 each
    //   CSR:   cnt[N] (reused as cursor), rowptr[N+1], esrc[E], partial[SCAN_B]
    char* ws = (char*)d_ws;
    unsigned short* Acat1 = (unsigned short*)ws;
    unsigned short* Acat2 = (unsigned short*)(ws + (size_t)NN * KC * 2);
    unsigned short* B1    = (unsigned short*)(ws + (size_t)NN * KC * 4);
    unsigned short* B2    = B1 + (size_t)DD * KC;
    int* cnt    = (int*)(ws + (size_t)NN * KC * 4 + (size_t)DD * KC * 4);
    int* rowptr = cnt + NN;
    int* esrc   = rowptr + NN + 1;
    int* partial = esrc + NE;

    // CSR build (hierarchical scan; no single-block serialization)
    hipMemsetAsync(cnt, 0, NN * sizeof(int), stream);
    k_hist<<<(NE + 255) / 256, 256, 0, stream>>>(dst, cnt);
    k_scan1<<<SCAN_B, 256, 0, stream>>>(cnt, rowptr, partial);
    k_scan2<<<1, 256, 0, stream>>>(partial);
    k_scan3<<<SCAN_B, 256, 0, stream>>>(rowptr, partial);
    hipMemsetAsync(cnt, 0, NN * sizeof(int), stream);  // reuse as cursor
    k_fill<<<(NE + 255) / 256, 256, 0, stream>>>(src, dst, rowptr, cnt, esrc);

    // converts
    k_convert_x<<<NN, 192, 0, stream>>>(x, Acat1);
    dim3 wgrid(DD, 2);
    k_convert_w<<<wgrid, 384, 0, stream>>>(W1l, W1r, W2l, W2r, B1, B2);

    dim3 ggrid((NN + 127) / 128, DD / 128);  // tm fast -> A streams once per tn-sweep, L3-resident after

    // layer 1 (aggregate bf16(x) from right half of Acat1)
    k_agg<<<NN, 192, 0, stream>>>(Acat1, rowptr, esrc, Acat1);
    k_gemm<0><<<ggrid, 256, 0, stream>>>(Acat1, B1, b1l, Acat2, nullptr);

    // layer 2
    k_agg<<<NN, 192, 0, stream>>>(Acat2, rowptr, esrc, Acat2);
    k_gemm<1><<<ggrid, 256, 0, stream>>>(Acat2, B2, b2l, nullptr, out);
}